// Round 17
// baseline (1678.812 us; speedup 1.0000x reference)
//
#include <hip/hip_runtime.h>
#include <hip/hip_fp16.h>

#define SEQT 2048
#define HID  256
#define NB   64

typedef int int32x4 __attribute__((ext_vector_type(4)));
typedef _Float16 h2 __attribute__((ext_vector_type(2)));

#define LOG2E 1.4426950408889634f
static __device__ __forceinline__ float tanhf_fast(float x) {
  float e = __builtin_amdgcn_exp2f(-2.f * LOG2E * fabsf(x));
  float r = (1.f - e) * __builtin_amdgcn_rcpf(1.f + e);
  return copysignf(r, x);
}
static __device__ __forceinline__ float max4(float4 f) {
  return fmaxf(fmaxf(fabsf(f.x), fabsf(f.y)), fmaxf(fabsf(f.z), fabsf(f.w)));
}
// quad_perm DPP (ctrl immediate; validated R10 on this HW)
template <int CTRL>
static __device__ __forceinline__ float dppf(float v) {
  int p = __builtin_amdgcn_update_dpp(0, __builtin_bit_cast(int, v), CTRL, 0xF, 0xF, true);
  return __builtin_bit_cast(float, p);
}
#define QP_XOR1 0xB1   // [1,0,3,2]
#define QP_XOR2 0x4E   // [2,3,0,1]

// One WG per batch (64 WGs), 1024 thr = 16 waves = 4 waves/SIMD. R14's shape
// (TLP for latency hiding) + R17's quad-split act (R14's failure was 4x act
// redundancy + AGPR traffic; R16 showed act is LATENCY-bound, needing TLP).
// Wave v owns units [16v,16v+16): tile q = gate-q rows q*256+16v+lm, 4 k-tiles
// -> 16 MFMA/wave/step (A-coverage floor; af 64 dw/thread fits 128-reg/wave
// budget at 4 waves/EU — R14-proven no-spill). D-cols are all identical, so
// unit->lane assignment is free: ru=lm>>2 (unit low bits), g=lm&3 (replica).
// The 4 replicas of unit u=16v+4ko+ru are an ADJACENT QUAD -> quad_perm DPP
// exchange (pure VALU). Replica g computes ONLY gate qmap[g] (g0=I,g1=G,g2=F,
// g3=O; qmap=bit-swap) via tanh-unified sigmoid; then:
//   B1=xor1(act): g0:G g1:I g2:O g3:F ; Pp=act*B1 (g0,g1: I*G)
//   Pv=xor2(Pp) (g2,g3: P) ; Fv=(g&1)?B1:act (g2,g3: F)
//   c'=fma(Fv,c,Pv) on g2,g3 ; c broadcast back via xor2 + cndmask
//   th=tanh(c) ; Ov=(g&1)?act:B1 (g2,g3: O) ; h=Ov*th ; writer g==3.
// Per-row scales; i8 h-ring(16) + f16 ring flushed to hist every 16 steps.
// Arithmetic family identical to R12/R16 (absmax ~3.4e-3).
__global__ __attribute__((amdgpu_flat_work_group_size(1024, 1024),
                          amdgpu_waves_per_eu(4, 4)))
void lstm_main(const float* __restrict__ x, const float* __restrict__ Wih,
               const float* __restrict__ Whh, const float* __restrict__ bih,
               const float* __restrict__ bhh, float* __restrict__ out,
               unsigned* __restrict__ hist)   // hist f16x2 dwords: [b][step][128]
{
  __shared__ __align__(16) unsigned char qring[16 * 256];   // i8 h ring
  __shared__ __align__(16) unsigned      f16r[16 * 128];    // f16 h ring
  __shared__ float xs[SEQT];
  __shared__ float rowS[1024];                              // per-row gate scale

  const int t    = threadIdx.x;
  const int b    = blockIdx.x;
  const int v    = t >> 6;          // wave 0..15
  const int lane = t & 63;
  const int ko   = lane >> 4;       // D-row-quad / k-16-group 0..3
  const int lm   = lane & 15;       // A-row within tile
  const int ru   = lm >> 2;         // unit low bits (elem/reg select)
  const int g    = lm & 3;          // replica: 0=I 1=G 2=F 3=O
  const int u    = 16 * v + 4 * ko + ru;             // this quad's unit
  const int qm   = ((g & 1) << 1) | (g >> 1);        // gate row index i,f,g,o

  ((float2*)xs)[t] = ((const float2*)(x + (size_t)b * SEQT))[t];
  if (t < 64) ((unsigned*)qring)[15 * 64 + t] = 0u;   // zero slot 15 (pre-step0)

  // ---- per-row max + quantize A-fragments (64 dw/thread) ----
  int32x4 af[4][4];
#pragma unroll
  for (int q = 0; q < 4; ++q) {
    const int row = q * 256 + 16 * v + lm;
    const float* rp = Whh + (size_t)row * HID + 16 * ko;
    float mx = 1e-20f;
#pragma unroll
    for (int kt = 0; kt < 4; ++kt) {
      const float4* p = (const float4*)(rp + 64 * kt);
      mx = fmaxf(mx, fmaxf(fmaxf(max4(p[0]), max4(p[1])),
                           fmaxf(max4(p[2]), max4(p[3]))));
    }
    mx = fmaxf(mx, __shfl_xor(mx, 16, 64));   // reduce across ko groups
    mx = fmaxf(mx, __shfl_xor(mx, 32, 64));
    const float winv = 127.f / mx;
    if (ko == 0) rowS[row] = mx * (1.f / (127.f * 127.f));
#pragma unroll
    for (int kt = 0; kt < 4; ++kt) {
      const float4* p = (const float4*)(rp + 64 * kt);
      int32x4 vv;
#pragma unroll
      for (int d = 0; d < 4; ++d) {
        float4 f = p[d];
        int q0 = (int)__builtin_rintf(f.x * winv);
        int q1 = (int)__builtin_rintf(f.y * winv);
        int q2 = (int)__builtin_rintf(f.z * winv);
        int q3 = (int)__builtin_rintf(f.w * winv);
        vv[d] = (q0 & 255) | ((q1 & 255) << 8) | ((q2 & 255) << 16) | ((q3 & 255) << 24);
      }
      af[q][kt] = vv;
    }
  }

  // this lane's single gate (qm) of unit u
  const int grow   = qm * 256 + u;
  const float biasg = bih[grow] + bhh[grow];
  const float wihg  = Wih[grow];
  // activation form: g==1 (G gate) pure tanh, else sigmoid=0.5*tanh(x/2)+0.5
  const float scg = (g == 1) ? 1.0f : 0.5f;
  const float amg = (g == 1) ? 1.0f : 0.5f;
  const float abg = (g == 1) ? 0.0f : 0.5f;
  __syncthreads();
  const float Sg = rowS[grow];

  unsigned* histb = hist + (size_t)b * SEQT * 128;
  float c = 0.f, h = 0.f;
  const int32x4 z4 = {0, 0, 0, 0};

  for (int s = 0; s < SEQT; ++s) {
    float xv = xs[s];
    const unsigned char* qs = qring + ((s + 15) & 15) * 256;
    int32x4 bf[4];
#pragma unroll
    for (int kt = 0; kt < 4; ++kt)
      bf[kt] = *(const int32x4*)(qs + 64 * kt + 16 * ko);   // broadcast b128

    // 16 MFMA: 4 independent 4-deep chains
    int32x4 acc[4];
#pragma unroll
    for (int q = 0; q < 4; ++q)
      acc[q] = __builtin_amdgcn_mfma_i32_16x16x64_i8(af[q][0], bf[0], z4, 0, 0, 0);
#pragma unroll
    for (int kt = 1; kt < 4; ++kt)
#pragma unroll
      for (int q = 0; q < 4; ++q)
        acc[q] = __builtin_amdgcn_mfma_i32_16x16x64_i8(af[q][kt], bf[kt], acc[q], 0, 0, 0);

    // ---- select acc[qm][ru] (both static-per-lane via cndmask trees) ----
    int32x4 A01 = (g & 2) ? acc[1] : acc[0];   // qm low bit = g>>1
    int32x4 A23 = (g & 2) ? acc[3] : acc[2];
    int32x4 Ag  = (g & 1) ? A23 : A01;         // qm high bit = g&1
    int e01 = (ru & 1) ? Ag[1] : Ag[0];
    int e23 = (ru & 1) ? Ag[3] : Ag[2];
    int gv  = (ru & 2) ? e23 : e01;

    float a   = __builtin_fmaf((float)gv, Sg, __builtin_fmaf(wihg, xv, biasg));
    float act = __builtin_fmaf(tanhf_fast(a * scg), amg, abg);  // I/G/F/O per g

    // ---- quad exchange: P=I*G, c=F*c+P, h=O*tanh(c) ----
    float B1 = dppf<QP_XOR1>(act);       // g0:G g1:I g2:O g3:F
    float Pp = act * B1;                 // g0,g1: I*G
    float Pv = dppf<QP_XOR2>(Pp);        // g2,g3: P
    float Fv = (g & 1) ? B1 : act;       // g2,g3: F
    float cn = __builtin_fmaf(Fv, c, Pv);   // valid on g2,g3
    float cb = dppf<QP_XOR2>(cn);        // g0,g1 <- g2,g3
    c = (g & 2) ? cn : cb;               // replica-consistent c
    float th = tanhf_fast(c);
    float Ov = (g & 1) ? act : B1;       // g2,g3: O
    h = Ov * th;                         // valid on g2,g3

    if (g == 3) {                        // one writer per unit
      int qv = (int)__builtin_rintf(h * 127.f);
      ((char*)qring)[(s & 15) * 256 + u]    = (char)qv;       // next B-source
      ((_Float16*)f16r)[(s & 15) * 256 + u] = (_Float16)h;    // hist ring
    }
    __syncthreads();                     // h ring ready for step s+1

    if ((s & 15) == 15) {                // flush 16 steps of h
      if (t < 512) {
        uint4 vv = *(const uint4*)(f16r + 4 * t);
        *(uint4*)(histb + (size_t)(s - 15) * 128 + 4 * t) = vv;
      }
      __syncthreads();                   // protect ring vs next writes
    }
  }

  if (g == 3) {
    out[NB * SEQT + b * HID + u]            = h;   // h_n
    out[NB * SEQT + NB * HID + b * HID + u] = c;   // c_n
  }
}

// y[b,t] = Wfc . h[b,t,:] + bfc  — one wave per output, coalesced 8B/lane loads.
__global__ __launch_bounds__(256) void lstm_head(
    const unsigned* __restrict__ hist, const float* __restrict__ Wfc,
    const float* __restrict__ bfc, float* __restrict__ y)
{
  int gw   = (blockIdx.x * 256 + threadIdx.x) >> 6;  // global wave id = output idx
  int lane = threadIdx.x & 63;
  uint2 hv = ((const uint2*)(hist + (size_t)gw * 128))[lane];
  float4 w = ((const float4*)Wfc)[lane];
  h2 p0 = __builtin_bit_cast(h2, hv.x);
  h2 p1 = __builtin_bit_cast(h2, hv.y);
  float s = (float)p0.x * w.x + (float)p0.y * w.y +
            (float)p1.x * w.z + (float)p1.y * w.w;
#pragma unroll
  for (int m = 32; m; m >>= 1) s += __shfl_xor(s, m, 64);
  if (lane == 0) y[gw] = s + bfc[0];
}

extern "C" void kernel_launch(void* const* d_in, const int* in_sizes, int n_in,
                              void* d_out, int out_size, void* d_ws, size_t ws_size,
                              hipStream_t stream)
{
  const float* x   = (const float*)d_in[0];
  const float* Wih = (const float*)d_in[1];
  const float* Whh = (const float*)d_in[2];
  const float* bih = (const float*)d_in[3];
  const float* bhh = (const float*)d_in[4];
  const float* Wfc = (const float*)d_in[5];
  const float* bfc = (const float*)d_in[6];
  float* out      = (float*)d_out;
  unsigned* hist  = (unsigned*)d_ws;   // 64*2048*128 dwords = 64 MiB

  (void)in_sizes; (void)n_in; (void)out_size; (void)ws_size;

  lstm_main<<<dim3(NB), dim3(1024), 0, stream>>>(x, Wih, Whh, bih, bhh, out, hist);
  lstm_head<<<dim3((NB * SEQT) / 4), dim3(256), 0, stream>>>(hist, Wfc, bfc, out);
}

// Round 18
// 1640.318 us; speedup vs baseline: 1.0235x; 1.0235x over previous
//
#include <hip/hip_runtime.h>
#include <hip/hip_fp16.h>

#define SEQT 2048
#define HID  256
#define NB   64

typedef int int32x4 __attribute__((ext_vector_type(4)));
typedef _Float16 h2 __attribute__((ext_vector_type(2)));

#define LOG2E 1.4426950408889634f
static __device__ __forceinline__ float sigf(float x) {
  return __builtin_amdgcn_rcpf(1.f + __builtin_amdgcn_exp2f(-LOG2E * x));
}
static __device__ __forceinline__ float tanhf_fast(float x) {
  float e = __builtin_amdgcn_exp2f(-2.f * LOG2E * fabsf(x));
  float r = (1.f - e) * __builtin_amdgcn_rcpf(1.f + e);
  return copysignf(r, x);
}
static __device__ __forceinline__ float max4(float4 f) {
  return fmaxf(fmaxf(fabsf(f.x), fabsf(f.y)), fmaxf(fabsf(f.z), fabsf(f.w)));
}

// R18 = byte-identical restore of R12 (best measured: 1643us), after R13-R17
// explored batch-pairing, 16-wave TLP, lds-only barriers, split/quad-split
// activations — all neutral or worse. Step structure (measured decomposition):
// MFMA A-coverage floor (~1020-1306cyc; all 256KB i8 weights stream through
// the matrix pipe every step) + act phase (~450-600cyc; data-dependent on the
// same wave's MFMA accs, lockstep barrier -> cannot overlap) + barrier/ds
// (~170-300). One WG (512 thr = 8 waves) per batch. Gates = Whh*h via
// mfma_i32_16x16x64_i8 (B = h broadcast to 16 cols). Wave w owns ALL FOUR
// gates of units [32w,32w+32): tile r=(q,sh) = rows q*256+32w+16sh (8 tiles x
// 4 k-tiles = 32 MFMA/wave/step = A-coverage floor). D-layout (HW-validated
// R11/R12): lane (ko,lm) reg j holds row 4ko+j of each tile, cols equal ->
// the SAME lane holds I,F,G,O of unit u = 32w+16su+4ko+ru. Activations
// in-register via static cndmask select tree; ONE barrier/step. Per-row
// weight scales; i8 h-ring (16 slots); f16 ring flushed to hist every 16.
__global__ __attribute__((amdgpu_flat_work_group_size(512, 512),
                          amdgpu_waves_per_eu(2, 2)))
void lstm_main(const float* __restrict__ x, const float* __restrict__ Wih,
               const float* __restrict__ Whh, const float* __restrict__ bih,
               const float* __restrict__ bhh, float* __restrict__ out,
               unsigned* __restrict__ hist)   // hist f16x2 dwords: [b][step][128]
{
  __shared__ __align__(16) unsigned char qring[16 * 256];   // i8 h ring
  __shared__ __align__(16) unsigned      f16r[16 * 128];    // f16 h ring
  __shared__ float xs[SEQT];
  __shared__ float rowS[1024];                              // per-row gate scale

  const int t    = threadIdx.x;
  const int b    = blockIdx.x;
  const int w    = t >> 6;
  const int lane = t & 63;
  const int ko   = lane >> 4;       // k-16-group / D-row-quad 0..3
  const int lm   = lane & 15;       // A-row within tile / D-col
  const int su   = (lm >> 2) & 1;   // tile-half this lane activates
  const int ru   = lm & 3;          // reg this lane activates
  const int u    = 32 * w + 16 * su + 4 * ko + ru;   // unit (dup for lm>=8)

  ((float4*)xs)[t] = ((const float4*)(x + (size_t)b * SEQT))[t];
  if (t < 64) ((unsigned*)qring)[15 * 64 + t] = 0u;   // zero slot 15 (h pre-step0)

  // ---- per-row max + quantize A-fragments (128 dw/thread -> AGPR) ----
  int32x4 af[8][4];
#pragma unroll
  for (int r = 0; r < 8; ++r) {
    const int q = r >> 1, sh = r & 1;
    const int row = q * 256 + 32 * w + 16 * sh + lm;
    const float* rp = Whh + (size_t)row * HID + 16 * ko;
    float mx = 1e-20f;
#pragma unroll
    for (int kt = 0; kt < 4; ++kt) {
      const float4* p = (const float4*)(rp + 64 * kt);
      mx = fmaxf(mx, fmaxf(fmaxf(max4(p[0]), max4(p[1])),
                           fmaxf(max4(p[2]), max4(p[3]))));
    }
    mx = fmaxf(mx, __shfl_xor(mx, 16, 64));   // reduce across ko groups
    mx = fmaxf(mx, __shfl_xor(mx, 32, 64));
    const float winv = 127.f / mx;
    if (ko == 0) rowS[row] = mx * (1.f / (127.f * 127.f));
#pragma unroll
    for (int kt = 0; kt < 4; ++kt) {
      const float4* p = (const float4*)(rp + 64 * kt);
      int32x4 v;
#pragma unroll
      for (int d = 0; d < 4; ++d) {
        float4 f = p[d];
        int q0 = (int)__builtin_rintf(f.x * winv);
        int q1 = (int)__builtin_rintf(f.y * winv);
        int q2 = (int)__builtin_rintf(f.z * winv);
        int q3 = (int)__builtin_rintf(f.w * winv);
        v[d] = (q0 & 255) | ((q1 & 255) << 8) | ((q2 & 255) << 16) | ((q3 & 255) << 24);
      }
      af[r][kt] = v;
    }
  }

  float biasu[4], wihu[4];
#pragma unroll
  for (int q = 0; q < 4; ++q) {
    int row = q * 256 + u;
    biasu[q] = bih[row] + bhh[row];
    wihu[q]  = Wih[row];
  }
  __syncthreads();
  float Su[4];
#pragma unroll
  for (int q = 0; q < 4; ++q) Su[q] = rowS[q * 256 + u];

  unsigned* histb = hist + (size_t)b * SEQT * 128;
  float c = 0.f, h = 0.f;
  const int32x4 z4 = {0, 0, 0, 0};

  for (int s = 0; s < SEQT; ++s) {
    float xv = xs[s];
    const unsigned char* qs = qring + ((s + 15) & 15) * 256;
    int32x4 bf[4];
#pragma unroll
    for (int kt = 0; kt < 4; ++kt)
      bf[kt] = *(const int32x4*)(qs + 64 * kt + 16 * ko);   // broadcast b128

    // 32 MFMA: 8 independent 4-deep chains
    int32x4 acc[8];
#pragma unroll
    for (int r = 0; r < 8; ++r)
      acc[r] = __builtin_amdgcn_mfma_i32_16x16x64_i8(af[r][0], bf[0], z4, 0, 0, 0);
#pragma unroll
    for (int kt = 1; kt < 4; ++kt)
#pragma unroll
      for (int r = 0; r < 8; ++r)
        acc[r] = __builtin_amdgcn_mfma_i32_16x16x64_i8(af[r][kt], bf[kt], acc[r], 0, 0, 0);

    // static select: gate q of unit u = acc[2q+su][ru]
    float aq[4];
#pragma unroll
    for (int q = 0; q < 4; ++q) {
      int32x4 v0 = acc[2 * q], v1 = acc[2 * q + 1];
      int e0 = su ? v1[0] : v0[0];
      int e1 = su ? v1[1] : v0[1];
      int e2 = su ? v1[2] : v0[2];
      int e3 = su ? v1[3] : v0[3];
      int g01 = (ru & 1) ? e1 : e0;
      int g23 = (ru & 1) ? e3 : e2;
      int gv  = (ru & 2) ? g23 : g01;
      aq[q] = __builtin_fmaf((float)gv, Su[q],
                             __builtin_fmaf(wihu[q], xv, biasu[q]));
    }

    float I = sigf(aq[0]), F = sigf(aq[1]), G = tanhf_fast(aq[2]), O = sigf(aq[3]);
    c = F * c + I * G;
    h = O * tanhf_fast(c);

    if (lm < 8) {                                  // one writer per unit
      int qv = (int)__builtin_rintf(h * 127.f);
      ((char*)qring)[(s & 15) * 256 + u]    = (char)qv;       // next B-source
      ((_Float16*)f16r)[(s & 15) * 256 + u] = (_Float16)h;    // hist ring
    }
    __syncthreads();                               // h ring ready for step s+1

    if ((s & 15) == 15) {                          // flush 16 steps of h
      uint4 v = *(const uint4*)(f16r + 4 * t);
      *(uint4*)(histb + (size_t)(s - 15) * 128 + 4 * t) = v;
      __syncthreads();                             // protect ring vs next writes
    }
  }

  if (lm < 8) {
    out[NB * SEQT + b * HID + u]            = h;   // h_n
    out[NB * SEQT + NB * HID + b * HID + u] = c;   // c_n
  }
}

// y[b,t] = Wfc . h[b,t,:] + bfc  — one wave per output, coalesced 8B/lane loads.
__global__ __launch_bounds__(256) void lstm_head(
    const unsigned* __restrict__ hist, const float* __restrict__ Wfc,
    const float* __restrict__ bfc, float* __restrict__ y)
{
  int gw   = (blockIdx.x * 256 + threadIdx.x) >> 6;  // global wave id = output idx
  int lane = threadIdx.x & 63;
  uint2 hv = ((const uint2*)(hist + (size_t)gw * 128))[lane];
  float4 w = ((const float4*)Wfc)[lane];
  h2 p0 = __builtin_bit_cast(h2, hv.x);
  h2 p1 = __builtin_bit_cast(h2, hv.y);
  float s = (float)p0.x * w.x + (float)p0.y * w.y +
            (float)p1.x * w.z + (float)p1.y * w.w;
#pragma unroll
  for (int m = 32; m; m >>= 1) s += __shfl_xor(s, m, 64);
  if (lane == 0) y[gw] = s + bfc[0];
}

extern "C" void kernel_launch(void* const* d_in, const int* in_sizes, int n_in,
                              void* d_out, int out_size, void* d_ws, size_t ws_size,
                              hipStream_t stream)
{
  const float* x   = (const float*)d_in[0];
  const float* Wih = (const float*)d_in[1];
  const float* Whh = (const float*)d_in[2];
  const float* bih = (const float*)d_in[3];
  const float* bhh = (const float*)d_in[4];
  const float* Wfc = (const float*)d_in[5];
  const float* bfc = (const float*)d_in[6];
  float* out      = (float*)d_out;
  unsigned* hist  = (unsigned*)d_ws;   // 64*2048*128 dwords = 64 MiB

  (void)in_sizes; (void)n_in; (void)out_size; (void)ws_size;

  lstm_main<<<dim3(NB), dim3(512), 0, stream>>>(x, Wih, Whh, bih, bhh, out, hist);
  lstm_head<<<dim3((NB * SEQT) / 4), dim3(256), 0, stream>>>(hist, Wfc, bfc, out);
}